// Round 2
// baseline (463.486 us; speedup 1.0000x reference)
//
#include <hip/hip_runtime.h>
#include <hip/hip_bf16.h>

typedef __attribute__((ext_vector_type(8))) short short8;
typedef __attribute__((ext_vector_type(4))) float floatx4;

#define B_ 8
#define C_IN 256
#define C_OUT 256
#define H_ 128
#define W_ 128
#define S_ 512
#define HW_ (H_*W_)
#define LIN_SCALE 0.04419417382415922f   /* 1/sqrt(512) */
#define CONV_SCALE 0.02083333333333333f  /* 1/sqrt(256*9) */
#define EPS_ 1e-8f

#define TT 16            /* 16x16 pixel tile */
#define PH 18
#define PW 18
#define NPIX (PH*PW)     /* 324 halo pixels */
#define NKB 72           /* 8 ci-chunks * 9 taps */
#define NITEM (8*NPIX)   /* 2592 staging items per ci-chunk (q, pix) */
#define NTHR 512

__device__ __forceinline__ unsigned short f2bf(float f) {
  unsigned u = __builtin_bit_cast(unsigned, f);
  u = (u + 0x7fffu + ((u >> 16) & 1u)) >> 16;
  return (unsigned short)u;
}

// ---------------- kernel 1: style modulation s[b][ci] ----------------
__global__ void k_style(const float* __restrict__ style, const float* __restrict__ mw,
                        const float* __restrict__ mb, float* __restrict__ s) {
  __shared__ float sty[S_];
  const int b = blockIdx.x;
  for (int i = threadIdx.x; i < S_; i += 256) sty[i] = style[b*S_ + i];
  __syncthreads();
  const int ci = threadIdx.x;  // 256 threads
  const float* wr = mw + (size_t)ci*S_;
  float acc = 0.f;
  for (int i = 0; i < S_; ++i) acc += sty[i] * wr[i];
  s[b*C_IN + ci] = acc * LIN_SCALE + mb[ci];
}

// ---------------- kernel 2: demod[b][co] ----------------
__global__ void k_demod(const float* __restrict__ weight, const float* __restrict__ s,
                        float* __restrict__ demod) {
  const int b = blockIdx.x >> 8, co = blockIdx.x & 255;
  const int l = threadIdx.x;  // 64 threads
  const float* wrow = weight + (size_t)co*C_IN*9;
  const float* sb = s + b*C_IN;
  float acc = 0.f;
  for (int idx = l; idx < C_IN*9; idx += 64) {
    float wv = wrow[idx] * sb[idx/9];
    acc += wv*wv;
  }
#pragma unroll
  for (int off = 32; off; off >>= 1) acc += __shfl_down(acc, off, 64);
  if (l == 0) demod[blockIdx.x] = rsqrtf(acc * (CONV_SCALE*CONV_SCALE) + EPS_);
}

// ---------------- kernel 3: pack modulated weights into MFMA A-fragment order ----------------
// layout: frag[((b*72 + kb)*16 + mt)*64 + lane][8] bf16, kb = ci_chunk*9 + tap
// A-frag lane l: co = mt*16 + (l&15), k_in = (l>>4)*8 + j, ci = chunk*32 + k_in
__global__ void k_pack(const float* __restrict__ weight, const float* __restrict__ s,
                       const float* __restrict__ demod, unsigned short* __restrict__ frag) {
  const int bid = blockIdx.x;            // (b*72 + kb)*16 + mt
  const int mt = bid & 15;
  const int kb = (bid >> 4) % NKB;
  const int b  = bid / (NKB*16);
  const int l = threadIdx.x;             // 64 threads
  const int co = mt*16 + (l & 15);
  const int chunk = kb / 9, r = kb % 9;
  const float dm = demod[b*C_OUT + co] * CONV_SCALE;
  const float* sb = s + b*C_IN;
  unsigned v[4];
#pragma unroll
  for (int jj = 0; jj < 4; ++jj) {
    int ci0 = chunk*32 + (l >> 4)*8 + jj*2;
    unsigned lo = f2bf(weight[((size_t)co*C_IN + ci0    )*9 + r] * sb[ci0    ] * dm);
    unsigned hi = f2bf(weight[((size_t)co*C_IN + ci0 + 1)*9 + r] * sb[ci0 + 1] * dm);
    v[jj] = lo | (hi << 16);
  }
  unsigned* dst = (unsigned*)(frag + (size_t)bid*512 + l*8);
  dst[0] = v[0]; dst[1] = v[1]; dst[2] = v[2]; dst[3] = v[3];
}

// ---------------- kernel 4: implicit-GEMM conv ----------------
// block: 256 co x (16x16) pixels, 512 threads, 8 waves as 4(M)x2(N)
// wave tile: 64 co x 128 px = 4(m) x 8(n) frags of 16x16
__launch_bounds__(NTHR, 2)
__global__ void k_conv(const float* __restrict__ x, const unsigned short* __restrict__ frag,
                       float* __restrict__ out) {
  __shared__ __align__(16) unsigned char lds[2][NPIX*64];
  const int bid = blockIdx.x;
  const int sx = bid & 7, sy = (bid >> 3) & 7, b = bid >> 6;
  const int h0 = sy*TT, w0 = sx*TT;
  const int tid = threadIdx.x;
  const int lane = tid & 63, wv = tid >> 6;
  const int wm = wv >> 1, wn = wv & 1;   // wm 0..3, wn 0..1

  const float* xb = x + (size_t)b*C_IN*HW_;
  const unsigned short* fb = frag + (size_t)b*NKB*16*512 + (size_t)lane*8;

  floatx4 acc[4][8];
#pragma unroll
  for (int m = 0; m < 4; ++m)
#pragma unroll
    for (int n = 0; n < 8; ++n) acc[m][n] = floatx4{0.f, 0.f, 0.f, 0.f};

  float pf[6][4];

  auto issue = [&](int c) {
#pragma unroll
    for (int i = 0; i < 6; ++i) {
      int item = tid + i*NTHR;
      if (item < NITEM) {
        int pw = item % PW;
        int t  = item / PW;
        int ph = t % PH;
        int q  = t / PH;                  // ci-quad 0..7
        int gh = h0 - 1 + ph, gw = w0 - 1 + pw;
        bool inb = ((unsigned)gh < (unsigned)H_) && ((unsigned)gw < (unsigned)W_);
        const float* p = xb + (size_t)(c*32 + q*4)*HW_ + gh*W_ + gw;
#pragma unroll
        for (int u = 0; u < 4; ++u)
          pf[i][u] = inb ? p[u*HW_] : 0.f;
      }
    }
  };
  auto commit = [&](int c) {
    int buf = c & 1;
#pragma unroll
    for (int i = 0; i < 6; ++i) {
      int item = tid + i*NTHR;
      if (item < NITEM) {
        int pw = item % PW;
        int t  = item / PW;
        int ph = t % PH;
        int q  = t / PH;
        int pix = ph*PW + pw;
        unsigned v0 = (unsigned)f2bf(pf[i][0]) | ((unsigned)f2bf(pf[i][1]) << 16);
        unsigned v1 = (unsigned)f2bf(pf[i][2]) | ((unsigned)f2bf(pf[i][3]) << 16);
        int slot = q >> 1, half = q & 1;
        int addr = pix*64 + ((slot ^ ((pix >> 1) & 3)) << 4) + half*8;
        unsigned* d = (unsigned*)(&lds[buf][addr]);
        d[0] = v0; d[1] = v1;
      }
    }
  };

  issue(0);
  commit(0);
  __syncthreads();

  for (int c = 0; c < 8; ++c) {
    if (c < 7) issue(c + 1);
    const unsigned char* cl = lds[c & 1];
#pragma unroll
    for (int r = 0; r < 9; ++r) {
      const int kb = c*9 + r;
      const int dh = r / 3, dw = r % 3;
      short8 a[4];
#pragma unroll
      for (int m = 0; m < 4; ++m) {
        int mt = wm*4 + m;
        a[m] = *(const short8*)(fb + (size_t)(kb*16 + mt)*512);
      }
      const int sl = lane >> 4;
#pragma unroll
      for (int n = 0; n < 8; ++n) {
        int nt = wn*8 + n;                 // pixel row within 16x16 tile
        int pix = (nt + dh)*PW + ((lane & 15) + dw);
        int addr = pix*64 + ((sl ^ ((pix >> 1) & 3)) << 4);
        short8 bb = *(const short8*)(cl + addr);
#pragma unroll
        for (int m = 0; m < 4; ++m)
          acc[m][n] = __builtin_amdgcn_mfma_f32_16x16x32_bf16(a[m], bb, acc[m][n], 0, 0, 0);
      }
    }
    if (c < 7) commit(c + 1);
    __syncthreads();
  }

  // epilogue: C/D layout col=lane&15 (pixel w), row=(lane>>4)*4+i (co within 16)
  float* ob = out + (size_t)b*C_OUT*HW_;
  const int tw = lane & 15, rg = lane >> 4;
#pragma unroll
  for (int m = 0; m < 4; ++m) {
#pragma unroll
    for (int n = 0; n < 8; ++n) {
      int co = (wm*4 + m)*16 + rg*4;
      int h = h0 + wn*8 + n;
      float* p = ob + (size_t)co*HW_ + (size_t)h*W_ + w0 + tw;
#pragma unroll
      for (int i = 0; i < 4; ++i) p[i*HW_] = acc[m][n][i];
    }
  }
}

extern "C" void kernel_launch(void* const* d_in, const int* in_sizes, int n_in,
                              void* d_out, int out_size, void* d_ws, size_t ws_size,
                              hipStream_t stream) {
  const float* x      = (const float*)d_in[0];
  const float* style  = (const float*)d_in[1];
  const float* weight = (const float*)d_in[2];
  const float* mod_w  = (const float*)d_in[3];
  const float* mod_b  = (const float*)d_in[4];
  float* out = (float*)d_out;
  char* ws = (char*)d_ws;

  float* s     = (float*)ws;                       // 2048 f32
  float* demod = (float*)(ws + 8192);              // 2048 f32
  unsigned short* frag = (unsigned short*)(ws + 16384); // 9.4 MB bf16 fragments

  k_style<<<B_, 256, 0, stream>>>(style, mod_w, mod_b, s);
  k_demod<<<B_*C_OUT, 64, 0, stream>>>(weight, s, demod);
  k_pack<<<B_*NKB*16, 64, 0, stream>>>(weight, s, demod, frag);
  k_conv<<<B_*8*8, NTHR, 0, stream>>>(x, frag, out);
}

// Round 3
// 458.113 us; speedup vs baseline: 1.0117x; 1.0117x over previous
//
#include <hip/hip_runtime.h>
#include <hip/hip_bf16.h>

typedef __attribute__((ext_vector_type(8))) short short8;
typedef __attribute__((ext_vector_type(4))) float floatx4;

#define B_ 8
#define C_IN 256
#define C_OUT 256
#define H_ 128
#define W_ 128
#define S_ 512
#define HW_ (H_*W_)
#define LIN_SCALE 0.04419417382415922f   /* 1/sqrt(512) */
#define CONV_SCALE 0.02083333333333333f  /* 1/sqrt(256*9) */
#define EPS_ 1e-8f

#define TT 16            /* 16x16 pixel tile */
#define PH 18
#define PW 18
#define NPIX (PH*PW)     /* 324 halo pixels */
#define NKB 72           /* 8 ci-chunks * 9 taps */
#define NITEM (8*NPIX)   /* 2592 staging items per ci-chunk (q, pix) */
#define NTHR 512

__device__ __forceinline__ unsigned short f2bf(float f) {
  unsigned u = __builtin_bit_cast(unsigned, f);
  u = (u + 0x7fffu + ((u >> 16) & 1u)) >> 16;
  return (unsigned short)u;
}

// ---------------- kernel 1: style modulation s[b][ci] ----------------
__global__ void k_style(const float* __restrict__ style, const float* __restrict__ mw,
                        const float* __restrict__ mb, float* __restrict__ s) {
  __shared__ float sty[S_];
  const int b = blockIdx.x;
  for (int i = threadIdx.x; i < S_; i += 256) sty[i] = style[b*S_ + i];
  __syncthreads();
  const int ci = threadIdx.x;  // 256 threads
  const float* wr = mw + (size_t)ci*S_;
  float acc = 0.f;
  for (int i = 0; i < S_; ++i) acc += sty[i] * wr[i];
  s[b*C_IN + ci] = acc * LIN_SCALE + mb[ci];
}

// ---------------- kernel 2: demod[b][co] ----------------
__global__ void k_demod(const float* __restrict__ weight, const float* __restrict__ s,
                        float* __restrict__ demod) {
  const int b = blockIdx.x >> 8, co = blockIdx.x & 255;
  const int l = threadIdx.x;  // 64 threads
  const float* wrow = weight + (size_t)co*C_IN*9;
  const float* sb = s + b*C_IN;
  float acc = 0.f;
  for (int idx = l; idx < C_IN*9; idx += 64) {
    float wv = wrow[idx] * sb[idx/9];
    acc += wv*wv;
  }
#pragma unroll
  for (int off = 32; off; off >>= 1) acc += __shfl_down(acc, off, 64);
  if (l == 0) demod[blockIdx.x] = rsqrtf(acc * (CONV_SCALE*CONV_SCALE) + EPS_);
}

// ---------------- kernel 3: pack modulated weights into MFMA A-fragment order ----------------
// layout: frag[((b*72 + kb)*16 + mt)*64 + lane][8] bf16, kb = ci_chunk*9 + tap
// A-frag lane l: co = mt*16 + (l&15), k_in = (l>>4)*8 + j, ci = chunk*32 + k_in
__global__ void k_pack(const float* __restrict__ weight, const float* __restrict__ s,
                       const float* __restrict__ demod, unsigned short* __restrict__ frag) {
  const int bid = blockIdx.x;            // (b*72 + kb)*16 + mt
  const int mt = bid & 15;
  const int kb = (bid >> 4) % NKB;
  const int b  = bid / (NKB*16);
  const int l = threadIdx.x;             // 64 threads
  const int co = mt*16 + (l & 15);
  const int chunk = kb / 9, r = kb % 9;
  const float dm = demod[b*C_OUT + co] * CONV_SCALE;
  const float* sb = s + b*C_IN;
  unsigned v[4];
#pragma unroll
  for (int jj = 0; jj < 4; ++jj) {
    int ci0 = chunk*32 + (l >> 4)*8 + jj*2;
    unsigned lo = f2bf(weight[((size_t)co*C_IN + ci0    )*9 + r] * sb[ci0    ] * dm);
    unsigned hi = f2bf(weight[((size_t)co*C_IN + ci0 + 1)*9 + r] * sb[ci0 + 1] * dm);
    v[jj] = lo | (hi << 16);
  }
  unsigned* dst = (unsigned*)(frag + (size_t)bid*512 + l*8);
  dst[0] = v[0]; dst[1] = v[1]; dst[2] = v[2]; dst[3] = v[3];
}

// ---------------- kernel 4: implicit-GEMM conv ----------------
// block: 256 co x (16x16) pixels, 512 threads, 8 waves as 4(M)x2(N)
// wave tile: 64 co x 128 px = 4(m) x 8(n) frags of 16x16
// __launch_bounds__(512, 1): 1 block/CU target -> VGPR cap 256 (acc[4][8]=128
// VGPRs must stay in registers; (512,2) capped VGPR at 128 and spilled acc,
// causing 260 MB/dispatch of scratch traffic in round 2)
__launch_bounds__(NTHR, 1)
__global__ void k_conv(const float* __restrict__ x, const unsigned short* __restrict__ frag,
                       float* __restrict__ out) {
  __shared__ __align__(16) unsigned char lds[2][NPIX*64];
  const int bid = blockIdx.x;
  const int sx = bid & 7, sy = (bid >> 3) & 7, b = bid >> 6;
  const int h0 = sy*TT, w0 = sx*TT;
  const int tid = threadIdx.x;
  const int lane = tid & 63, wv = tid >> 6;
  const int wm = wv >> 1, wn = wv & 1;   // wm 0..3, wn 0..1

  const float* xb = x + (size_t)b*C_IN*HW_;
  const unsigned short* fb = frag + (size_t)b*NKB*16*512 + (size_t)lane*8;

  floatx4 acc[4][8];
#pragma unroll
  for (int m = 0; m < 4; ++m)
#pragma unroll
    for (int n = 0; n < 8; ++n) acc[m][n] = floatx4{0.f, 0.f, 0.f, 0.f};

  float pf[6][4];

  auto issue = [&](int c) {
#pragma unroll
    for (int i = 0; i < 6; ++i) {
      int item = tid + i*NTHR;
      if (item < NITEM) {
        int pw = item % PW;
        int t  = item / PW;
        int ph = t % PH;
        int q  = t / PH;                  // ci-quad 0..7
        int gh = h0 - 1 + ph, gw = w0 - 1 + pw;
        bool inb = ((unsigned)gh < (unsigned)H_) && ((unsigned)gw < (unsigned)W_);
        const float* p = xb + (size_t)(c*32 + q*4)*HW_ + gh*W_ + gw;
#pragma unroll
        for (int u = 0; u < 4; ++u)
          pf[i][u] = inb ? p[u*HW_] : 0.f;
      }
    }
  };
  auto commit = [&](int c) {
    int buf = c & 1;
#pragma unroll
    for (int i = 0; i < 6; ++i) {
      int item = tid + i*NTHR;
      if (item < NITEM) {
        int pw = item % PW;
        int t  = item / PW;
        int ph = t % PH;
        int q  = t / PH;
        int pix = ph*PW + pw;
        unsigned v0 = (unsigned)f2bf(pf[i][0]) | ((unsigned)f2bf(pf[i][1]) << 16);
        unsigned v1 = (unsigned)f2bf(pf[i][2]) | ((unsigned)f2bf(pf[i][3]) << 16);
        int slot = q >> 1, half = q & 1;
        int addr = pix*64 + ((slot ^ ((pix >> 1) & 3)) << 4) + half*8;
        unsigned* d = (unsigned*)(&lds[buf][addr]);
        d[0] = v0; d[1] = v1;
      }
    }
  };

  issue(0);
  commit(0);
  __syncthreads();

  for (int c = 0; c < 8; ++c) {
    if (c < 7) issue(c + 1);
    const unsigned char* cl = lds[c & 1];
#pragma unroll
    for (int r = 0; r < 9; ++r) {
      const int kb = c*9 + r;
      const int dh = r / 3, dw = r % 3;
      short8 a[4];
#pragma unroll
      for (int m = 0; m < 4; ++m) {
        int mt = wm*4 + m;
        a[m] = *(const short8*)(fb + (size_t)(kb*16 + mt)*512);
      }
      const int sl = lane >> 4;
#pragma unroll
      for (int n = 0; n < 8; ++n) {
        int nt = wn*8 + n;                 // pixel row within 16x16 tile
        int pix = (nt + dh)*PW + ((lane & 15) + dw);
        int addr = pix*64 + ((sl ^ ((pix >> 1) & 3)) << 4);
        short8 bb = *(const short8*)(cl + addr);
#pragma unroll
        for (int m = 0; m < 4; ++m)
          acc[m][n] = __builtin_amdgcn_mfma_f32_16x16x32_bf16(a[m], bb, acc[m][n], 0, 0, 0);
      }
    }
    if (c < 7) commit(c + 1);
    __syncthreads();
  }

  // epilogue: C/D layout col=lane&15 (pixel w), row=(lane>>4)*4+i (co within 16)
  float* ob = out + (size_t)b*C_OUT*HW_;
  const int tw = lane & 15, rg = lane >> 4;
#pragma unroll
  for (int m = 0; m < 4; ++m) {
#pragma unroll
    for (int n = 0; n < 8; ++n) {
      int co = (wm*4 + m)*16 + rg*4;
      int h = h0 + wn*8 + n;
      float* p = ob + (size_t)co*HW_ + (size_t)h*W_ + w0 + tw;
#pragma unroll
      for (int i = 0; i < 4; ++i) p[i*HW_] = acc[m][n][i];
    }
  }
}

extern "C" void kernel_launch(void* const* d_in, const int* in_sizes, int n_in,
                              void* d_out, int out_size, void* d_ws, size_t ws_size,
                              hipStream_t stream) {
  const float* x      = (const float*)d_in[0];
  const float* style  = (const float*)d_in[1];
  const float* weight = (const float*)d_in[2];
  const float* mod_w  = (const float*)d_in[3];
  const float* mod_b  = (const float*)d_in[4];
  float* out = (float*)d_out;
  char* ws = (char*)d_ws;

  float* s     = (float*)ws;                       // 2048 f32
  float* demod = (float*)(ws + 8192);              // 2048 f32
  unsigned short* frag = (unsigned short*)(ws + 16384); // 9.4 MB bf16 fragments

  k_style<<<B_, 256, 0, stream>>>(style, mod_w, mod_b, s);
  k_demod<<<B_*C_OUT, 64, 0, stream>>>(weight, s, demod);
  k_pack<<<B_*NKB*16, 64, 0, stream>>>(weight, s, demod, frag);
  k_conv<<<B_*8*8, NTHR, 0, stream>>>(x, frag, out);
}

// Round 4
// 440.720 us; speedup vs baseline: 1.0517x; 1.0395x over previous
//
#include <hip/hip_runtime.h>
#include <hip/hip_bf16.h>

typedef __attribute__((ext_vector_type(8))) short short8;
typedef __attribute__((ext_vector_type(4))) float floatx4;

#define B_ 8
#define C_IN 256
#define C_OUT 256
#define H_ 128
#define W_ 128
#define S_ 512
#define HW_ (H_*W_)
#define LIN_SCALE 0.04419417382415922f   /* 1/sqrt(512) */
#define CONV_SCALE 0.02083333333333333f  /* 1/sqrt(256*9) */
#define EPS_ 1e-8f

#define TT 16            /* 16x16 pixel tile */
#define PH 18
#define PW 18
#define NPIX (PH*PW)     /* 324 halo pixels */
#define NKB 72           /* 8 ci-chunks * 9 taps */
#define NITEM (8*NPIX)   /* 2592 staging items per ci-chunk (q, pix) */
#define NTHR 256         /* 4 waves: 2(M) x 2(N) */

__device__ __forceinline__ unsigned short f2bf(float f) {
  unsigned u = __builtin_bit_cast(unsigned, f);
  u = (u + 0x7fffu + ((u >> 16) & 1u)) >> 16;
  return (unsigned short)u;
}

// ---------------- kernel 1: style modulation s[b][ci] ----------------
__global__ void k_style(const float* __restrict__ style, const float* __restrict__ mw,
                        const float* __restrict__ mb, float* __restrict__ s) {
  __shared__ float sty[S_];
  const int b = blockIdx.x;
  for (int i = threadIdx.x; i < S_; i += 256) sty[i] = style[b*S_ + i];
  __syncthreads();
  const int ci = threadIdx.x;  // 256 threads
  const float* wr = mw + (size_t)ci*S_;
  float acc = 0.f;
  for (int i = 0; i < S_; ++i) acc += sty[i] * wr[i];
  s[b*C_IN + ci] = acc * LIN_SCALE + mb[ci];
}

// ---------------- kernel 2: demod[b][co] ----------------
__global__ void k_demod(const float* __restrict__ weight, const float* __restrict__ s,
                        float* __restrict__ demod) {
  const int b = blockIdx.x >> 8, co = blockIdx.x & 255;
  const int l = threadIdx.x;  // 64 threads
  const float* wrow = weight + (size_t)co*C_IN*9;
  const float* sb = s + b*C_IN;
  float acc = 0.f;
  for (int idx = l; idx < C_IN*9; idx += 64) {
    float wv = wrow[idx] * sb[idx/9];
    acc += wv*wv;
  }
#pragma unroll
  for (int off = 32; off; off >>= 1) acc += __shfl_down(acc, off, 64);
  if (l == 0) demod[blockIdx.x] = rsqrtf(acc * (CONV_SCALE*CONV_SCALE) + EPS_);
}

// ---------------- kernel 3: pack modulated weights into MFMA A-fragment order ----------------
// layout: frag[((b*72 + kb)*16 + mt)*64 + lane][8] bf16, kb = ci_chunk*9 + tap
// A-frag lane l: co = mt*16 + (l&15), k_in = (l>>4)*8 + j, ci = chunk*32 + k_in
__global__ void k_pack(const float* __restrict__ weight, const float* __restrict__ s,
                       const float* __restrict__ demod, unsigned short* __restrict__ frag) {
  const int bid = blockIdx.x;            // (b*72 + kb)*16 + mt
  const int mt = bid & 15;
  const int kb = (bid >> 4) % NKB;
  const int b  = bid / (NKB*16);
  const int l = threadIdx.x;             // 64 threads
  const int co = mt*16 + (l & 15);
  const int chunk = kb / 9, r = kb % 9;
  const float dm = demod[b*C_OUT + co] * CONV_SCALE;
  const float* sb = s + b*C_IN;
  unsigned v[4];
#pragma unroll
  for (int jj = 0; jj < 4; ++jj) {
    int ci0 = chunk*32 + (l >> 4)*8 + jj*2;
    unsigned lo = f2bf(weight[((size_t)co*C_IN + ci0    )*9 + r] * sb[ci0    ] * dm);
    unsigned hi = f2bf(weight[((size_t)co*C_IN + ci0 + 1)*9 + r] * sb[ci0 + 1] * dm);
    v[jj] = lo | (hi << 16);
  }
  unsigned* dst = (unsigned*)(frag + (size_t)bid*512 + l*8);
  dst[0] = v[0]; dst[1] = v[1]; dst[2] = v[2]; dst[3] = v[3];
}

// ---------------- kernel 4: implicit-GEMM conv ----------------
// block: 128 co x (16x16=256) pixels, 256 threads, 4 waves as 2(M)x2(N)
// wave tile: 64 co x 128 px = 4(m) x 8(n) frags of 16x16 (acc = 128 AGPRs)
// __launch_bounds__(256,2): 2 blocks/CU -> 2 waves/SIMD, 256 regs/wave
//   (128 AGPR acc + <=128 VGPR). Round-2/3 lesson: 8-wave blocks pin the
//   unified-file cap at exactly acc+128 with zero prefetch headroom and
//   1 block/CU (no TLP across barriers).
// Chunked XCD swizzle: XCD x runs exactly batch x -> frag set (1.18 MB)
//   L2-resident; co-pair/sx-neighbor blocks share input + merge output
//   half-lines in the same L2.
__launch_bounds__(NTHR, 2)
__global__ void k_conv(const float* __restrict__ x, const unsigned short* __restrict__ frag,
                       float* __restrict__ out) {
  __shared__ __align__(16) unsigned char lds[2][NPIX*64];
  // swizzle: position p -> XCD p%8 (round-robin heuristic); give XCD x the
  // contiguous work chunk [x*128, (x+1)*128) = all of batch x.
  const int work = (blockIdx.x & 7)*128 + (blockIdx.x >> 3);
  const int ct = work & 1;
  const int w2 = work >> 1;
  const int sx = w2 & 7, sy = (w2 >> 3) & 7, b = w2 >> 6;
  const int h0 = sy*TT, w0 = sx*TT;
  const int tid = threadIdx.x;
  const int lane = tid & 63, wv = tid >> 6;
  const int wm = wv >> 1, wn = wv & 1;   // wm 0..1, wn 0..1

  const float* xb = x + (size_t)b*C_IN*HW_;
  const unsigned short* fb = frag + (size_t)b*NKB*16*512 + (size_t)lane*8;

  floatx4 acc[4][8];
#pragma unroll
  for (int m = 0; m < 4; ++m)
#pragma unroll
    for (int n = 0; n < 8; ++n) acc[m][n] = floatx4{0.f, 0.f, 0.f, 0.f};

  // fused stage: global load -> bf16 pack -> LDS write (TLP covers latency)
  auto stage = [&](int c) {
    int buf = c & 1;
#pragma unroll
    for (int i = 0; i < 11; ++i) {
      int item = tid + i*NTHR;
      if (item < NITEM) {
        int pw = item % PW;
        int t  = item / PW;
        int ph = t % PH;
        int q  = t / PH;                  // ci-quad 0..7
        int gh = h0 - 1 + ph, gw = w0 - 1 + pw;
        bool inb = ((unsigned)gh < (unsigned)H_) && ((unsigned)gw < (unsigned)W_);
        const float* p = xb + (size_t)(c*32 + q*4)*HW_ + gh*W_ + gw;
        float f0 = inb ? p[0] : 0.f;
        float f1 = inb ? p[HW_] : 0.f;
        float f2 = inb ? p[2*HW_] : 0.f;
        float f3 = inb ? p[3*HW_] : 0.f;
        int pix = ph*PW + pw;
        unsigned v0 = (unsigned)f2bf(f0) | ((unsigned)f2bf(f1) << 16);
        unsigned v1 = (unsigned)f2bf(f2) | ((unsigned)f2bf(f3) << 16);
        int slot = q >> 1, half = q & 1;
        int addr = pix*64 + ((slot ^ ((pix >> 1) & 3)) << 4) + half*8;
        unsigned* d = (unsigned*)(&lds[buf][addr]);
        d[0] = v0; d[1] = v1;
      }
    }
  };

  stage(0);
  __syncthreads();

  for (int c = 0; c < 8; ++c) {
    if (c < 7) stage(c + 1);             // writes buf (c+1)&1; reads nothing from buf c&1
    const unsigned char* cl = lds[c & 1];
#pragma unroll
    for (int r = 0; r < 9; ++r) {
      const int kb = c*9 + r;
      const int dh = r / 3, dw = r % 3;
      short8 a[4];
#pragma unroll
      for (int m = 0; m < 4; ++m) {
        int mt = ct*8 + wm*4 + m;
        a[m] = *(const short8*)(fb + (size_t)(kb*16 + mt)*512);
      }
      const int sl = lane >> 4;
#pragma unroll
      for (int n = 0; n < 8; ++n) {
        int nt = wn*8 + n;                 // pixel row within 16x16 tile
        int pix = (nt + dh)*PW + ((lane & 15) + dw);
        int addr = pix*64 + ((sl ^ ((pix >> 1) & 3)) << 4);
        short8 bb = *(const short8*)(cl + addr);
#pragma unroll
        for (int m = 0; m < 4; ++m)
          acc[m][n] = __builtin_amdgcn_mfma_f32_16x16x32_bf16(a[m], bb, acc[m][n], 0, 0, 0);
      }
    }
    __syncthreads();
  }

  // epilogue: C/D layout col=lane&15 (pixel w), row=(lane>>4)*4+i (co within 16)
  float* ob = out + ((size_t)b*C_OUT + ct*128)*HW_;
  const int tw = lane & 15, rg = lane >> 4;
#pragma unroll
  for (int m = 0; m < 4; ++m) {
#pragma unroll
    for (int n = 0; n < 8; ++n) {
      int co = (wm*4 + m)*16 + rg*4;
      int h = h0 + wn*8 + n;
      float* p = ob + (size_t)co*HW_ + (size_t)h*W_ + w0 + tw;
#pragma unroll
      for (int i = 0; i < 4; ++i) p[i*HW_] = acc[m][n][i];
    }
  }
}

extern "C" void kernel_launch(void* const* d_in, const int* in_sizes, int n_in,
                              void* d_out, int out_size, void* d_ws, size_t ws_size,
                              hipStream_t stream) {
  const float* x      = (const float*)d_in[0];
  const float* style  = (const float*)d_in[1];
  const float* weight = (const float*)d_in[2];
  const float* mod_w  = (const float*)d_in[3];
  const float* mod_b  = (const float*)d_in[4];
  float* out = (float*)d_out;
  char* ws = (char*)d_ws;

  float* s     = (float*)ws;                       // 2048 f32
  float* demod = (float*)(ws + 8192);              // 2048 f32
  unsigned short* frag = (unsigned short*)(ws + 16384); // 9.4 MB bf16 fragments

  k_style<<<B_, 256, 0, stream>>>(style, mod_w, mod_b, s);
  k_demod<<<B_*C_OUT, 64, 0, stream>>>(weight, s, demod);
  k_pack<<<B_*NKB*16, 64, 0, stream>>>(weight, s, demod, frag);
  k_conv<<<B_*2*8*8, NTHR, 0, stream>>>(x, frag, out);
}

// Round 5
// 410.403 us; speedup vs baseline: 1.1293x; 1.0739x over previous
//
#include <hip/hip_runtime.h>
#include <hip/hip_bf16.h>

typedef __attribute__((ext_vector_type(8))) short short8;
typedef __attribute__((ext_vector_type(4))) float floatx4;
typedef __attribute__((ext_vector_type(4))) unsigned uint4v;

#define B_ 8
#define C_IN 256
#define C_OUT 256
#define H_ 128
#define W_ 128
#define S_ 512
#define HW_ (H_*W_)
#define LIN_SCALE 0.04419417382415922f   /* 1/sqrt(512) */
#define CONV_SCALE 0.02083333333333333f  /* 1/sqrt(256*9) */
#define EPS_ 1e-8f

#define XPH 130          /* padded H: rows -1..128 -> 0..129 */
#define XPW 136          /* padded W: cols -1..134 -> 0..135 (16B-align friendly) */
#define TTH 8            /* output tile 8h x 32w = 256 px (full 128B out lines) */
#define TTW 32
#define PH2 10           /* halo patch 10 x 34 */
#define PW2 34
#define NPIX2 (PH2*PW2)  /* 340 */
#define NITEM2 (NPIX2*4) /* 1360 16B-items per ci-chunk */
#define NKB 72           /* 8 ci-chunks * 9 taps */
#define NTHR 256         /* 4 waves: 2(M) x 2(N) */

__device__ __forceinline__ unsigned short f2bf(float f) {
  unsigned u = __builtin_bit_cast(unsigned, f);
  u = (u + 0x7fffu + ((u >> 16) & 1u)) >> 16;
  return (unsigned short)u;
}
__device__ __forceinline__ unsigned pack2(float a, float b) {
  return (unsigned)f2bf(a) | ((unsigned)f2bf(b) << 16);
}
__device__ __forceinline__ void gload16(const void* g, void* l) {
  __builtin_amdgcn_global_load_lds(
      (const __attribute__((address_space(1))) unsigned*)g,
      (__attribute__((address_space(3))) unsigned*)l, 16, 0, 0);
}

// ---------------- kernel 1: style modulation s[b][ci] ----------------
__global__ void k_style(const float* __restrict__ style, const float* __restrict__ mw,
                        const float* __restrict__ mb, float* __restrict__ s) {
  __shared__ float sty[S_];
  const int b = blockIdx.x;
  for (int i = threadIdx.x; i < S_; i += 256) sty[i] = style[b*S_ + i];
  __syncthreads();
  const int ci = threadIdx.x;  // 256 threads
  const float* wr = mw + (size_t)ci*S_;
  float acc = 0.f;
  for (int i = 0; i < S_; ++i) acc += sty[i] * wr[i];
  s[b*C_IN + ci] = acc * LIN_SCALE + mb[ci];
}

// ---------------- kernel 2: demod[b][co] ----------------
__global__ void k_demod(const float* __restrict__ weight, const float* __restrict__ s,
                        float* __restrict__ demod) {
  const int b = blockIdx.x >> 8, co = blockIdx.x & 255;
  const int l = threadIdx.x;  // 64 threads
  const float* wrow = weight + (size_t)co*C_IN*9;
  const float* sb = s + b*C_IN;
  float acc = 0.f;
  for (int idx = l; idx < C_IN*9; idx += 64) {
    float wv = wrow[idx] * sb[idx/9];
    acc += wv*wv;
  }
#pragma unroll
  for (int off = 32; off; off >>= 1) acc += __shfl_down(acc, off, 64);
  if (l == 0) demod[blockIdx.x] = rsqrtf(acc * (CONV_SCALE*CONV_SCALE) + EPS_);
}

// ---------------- kernel 3: pack modulated weights into MFMA A-fragment order ----------------
// layout: frag[((b*72 + kb)*16 + mt)*64 + lane][8] bf16, kb = ci_chunk*9 + tap
// A-frag lane l: co = mt*16 + (l&15), k_in = (l>>4)*8 + j, ci = chunk*32 + k_in
__global__ void k_pack(const float* __restrict__ weight, const float* __restrict__ s,
                       const float* __restrict__ demod, unsigned short* __restrict__ frag) {
  const int bid = blockIdx.x;            // (b*72 + kb)*16 + mt
  const int mt = bid & 15;
  const int kb = (bid >> 4) % NKB;
  const int b  = bid / (NKB*16);
  const int l = threadIdx.x;             // 64 threads
  const int co = mt*16 + (l & 15);
  const int chunk = kb / 9, r = kb % 9;
  const float dm = demod[b*C_OUT + co] * CONV_SCALE;
  const float* sb = s + b*C_IN;
  unsigned v[4];
#pragma unroll
  for (int jj = 0; jj < 4; ++jj) {
    int ci0 = chunk*32 + (l >> 4)*8 + jj*2;
    unsigned lo = f2bf(weight[((size_t)co*C_IN + ci0    )*9 + r] * sb[ci0    ] * dm);
    unsigned hi = f2bf(weight[((size_t)co*C_IN + ci0 + 1)*9 + r] * sb[ci0 + 1] * dm);
    v[jj] = lo | (hi << 16);
  }
  unsigned* dst = (unsigned*)(frag + (size_t)bid*512 + l*8);
  dst[0] = v[0]; dst[1] = v[1]; dst[2] = v[2]; dst[3] = v[3];
}

// ---------------- kernel 3b: zero-fill xpad ----------------
__global__ void k_zero(uint4v* __restrict__ p, int n) {
  int i = blockIdx.x*256 + threadIdx.x;
  const int stride = gridDim.x*256;
  const uint4v z = {0u,0u,0u,0u};
  for (; i < n; i += stride) p[i] = z;
}

// ---------------- kernel 3c: NCHW f32 -> padded NHWC bf16 ----------------
// xpad[b][hh][ww][ci] bf16, hh = h+1 (0..129), ww = w+1 (0..135); borders zero.
// Block: one b, one h-row, 64 px. LDS transpose [64px][256ci] with 16B-group
// XOR swizzle g' = g ^ ((px>>2)&7) (write 2-way, read 4-way banks).
__global__ void k_xpose(const float* __restrict__ x, unsigned short* __restrict__ xp) {
  __shared__ __align__(16) unsigned lds32[64*128];   // 32 KB
  const int bid = blockIdx.x;          // 8b * 128h * 2
  const int half = bid & 1, h = (bid >> 1) & 127, b = bid >> 8;
  const int w0 = half*64;
  const int t = threadIdx.x;
  const float* xr = x + (size_t)b*C_IN*HW_ + (size_t)h*W_ + w0;
#pragma unroll
  for (int j = 0; j < 8; ++j) {
    int cp = j*16 + (t >> 4);          // ci-pair 0..127
    int ci = cp*2;
    const float* p0 = xr + (size_t)ci*HW_ + (t & 15)*4;
    floatx4 f0 = *(const floatx4*)p0;
    floatx4 f1 = *(const floatx4*)(p0 + HW_);
    int g = cp >> 2, slot = cp & 3;
#pragma unroll
    for (int k = 0; k < 4; ++k) {
      int px = (t & 15)*4 + k;
      lds32[px*128 + ((g ^ ((px >> 2) & 7)) << 2) + slot] = pack2(f0[k], f1[k]);
    }
  }
  __syncthreads();
  unsigned short* dstb = xp + ((size_t)(b*XPH + h + 1)*XPW + (w0 + 1))*256;
#pragma unroll
  for (int i = 0; i < 8; ++i) {
    int item = i*256 + t;
    int px = item >> 5, g = item & 31;
    int gs = g ^ ((px >> 2) & 7);
    uint4v v = *(const uint4v*)&lds32[px*128 + (gs << 2)];
    *(uint4v*)(dstb + (size_t)px*256 + g*8) = v;
  }
}

// ---------------- kernel 4: implicit-GEMM conv ----------------
// block: 128 co (ct half) x (8h x 32w = 256 px), 256 threads, 4 waves 2(M)x2(N)
// wave tile: 64 co x 128 px = 4(m) x 8(n) frags of 16x16; acc = 128 AGPR
// Staging: global_load_lds 16B direct from padded-NHWC bf16 (async; no VGPR
// round-trip, no pack VALU, no edge masks). Source pre-swizzled with the
// B-read bank swizzle (slot ^ ((pix>>1)&3)); LDS dest linear (rule #21).
__launch_bounds__(NTHR, 2)
__global__ void k_conv(const unsigned short* __restrict__ xpad,
                       const unsigned short* __restrict__ frag,
                       float* __restrict__ out) {
  __shared__ __align__(16) unsigned char lds[2][1536*16];  // 48 KB (>= 1360 items)
  // XCD chunk swizzle: XCD x <- batch x; within XCD: ct pairs adjacent, then sx.
  const int work = (blockIdx.x & 7)*128 + (blockIdx.x >> 3);
  const int ct = work & 1;
  const int w2 = work >> 1;
  const int sx = w2 & 3, sy = (w2 >> 2) & 15, b = w2 >> 6;
  const int h0 = sy*TTH, w0 = sx*TTW;
  const int tid = threadIdx.x;
  const int lane = tid & 63, wv = tid >> 6;
  const int wm = wv >> 1, wn = wv & 1;

  // patch origin in padded coords: row h0-1+1 = h0, col w0-1+1 = w0 (pads cancel)
  const unsigned short* xbp = xpad + ((size_t)(b*XPH + h0)*XPW + w0)*256;
  const unsigned short* fb = frag + (size_t)b*NKB*16*512 + (size_t)lane*8;

  floatx4 acc[4][8];
#pragma unroll
  for (int m = 0; m < 4; ++m)
#pragma unroll
    for (int n = 0; n < 8; ++n) acc[m][n] = floatx4{0.f, 0.f, 0.f, 0.f};

  auto stage = [&](int c) {
    unsigned char* buf = lds[c & 1];
#pragma unroll
    for (int i = 0; i < 6; ++i) {
      int item = tid + i*NTHR;
      if (i < 5 || tid < (NITEM2 - 5*NTHR)) {
        int px = item >> 2, q8s = item & 3;
        int ph = px / PW2, pw = px - ph*PW2;
        int q8 = q8s ^ ((px >> 1) & 3);          // pre-swizzled SOURCE
        const unsigned short* src = xbp + ((size_t)ph*XPW + pw)*256 + c*32 + q8*8;
        gload16(src, buf + item*16);
      }
    }
  };

  stage(0);
  __syncthreads();   // vmcnt drain -> buf0 ready

  for (int c = 0; c < 8; ++c) {
    if (c < 7) stage(c + 1);           // async into other buffer
    const unsigned char* cl = lds[c & 1];
    const int sl = lane >> 4, c15 = lane & 15;
#pragma unroll
    for (int r = 0; r < 9; ++r) {
      const int kb = c*9 + r;
      const int dh = r / 3, dw = r % 3;
      short8 a[4];
#pragma unroll
      for (int m = 0; m < 4; ++m) {
        int mt = ct*8 + wm*4 + m;
        a[m] = *(const short8*)(fb + (size_t)(kb*16 + mt)*512);
      }
#pragma unroll
      for (int n = 0; n < 8; ++n) {
        int nt = wn*8 + n;                   // 16-px group: h = nt>>1, w-half = nt&1
        int ph = (nt >> 1) + dh;
        int pw = (nt & 1)*16 + c15 + dw;
        int pix = ph*PW2 + pw;
        int addr = pix*64 + ((sl ^ ((pix >> 1) & 3)) << 4);
        short8 bb = *(const short8*)(cl + addr);
#pragma unroll
        for (int m = 0; m < 4; ++m)
          acc[m][n] = __builtin_amdgcn_mfma_f32_16x16x32_bf16(a[m], bb, acc[m][n], 0, 0, 0);
      }
    }
    __syncthreads();   // drains stage(c+1) loads; releases buf c&1 for stage(c+2)
  }

  // epilogue: C/D col=lane&15 (pixel w), row=(lane>>4)*4+i (co)
  float* ob = out + ((size_t)b*C_OUT + ct*128)*HW_;
  const int tw = lane & 15, rg = lane >> 4;
#pragma unroll
  for (int m = 0; m < 4; ++m) {
#pragma unroll
    for (int n = 0; n < 8; ++n) {
      int co = (wm*4 + m)*16 + rg*4;
      int nt = wn*8 + n;
      int h = h0 + (nt >> 1);
      int w = w0 + (nt & 1)*16 + tw;
      float* p = ob + (size_t)co*HW_ + (size_t)h*W_ + w;
#pragma unroll
      for (int i = 0; i < 4; ++i) p[i*HW_] = acc[m][n][i];
    }
  }
}

extern "C" void kernel_launch(void* const* d_in, const int* in_sizes, int n_in,
                              void* d_out, int out_size, void* d_ws, size_t ws_size,
                              hipStream_t stream) {
  const float* x      = (const float*)d_in[0];
  const float* style  = (const float*)d_in[1];
  const float* weight = (const float*)d_in[2];
  const float* mod_w  = (const float*)d_in[3];
  const float* mod_b  = (const float*)d_in[4];
  float* out = (float*)d_out;
  char* ws = (char*)d_ws;

  float* s     = (float*)ws;                            // 8 KB
  float* demod = (float*)(ws + 8192);                   // 8 KB
  unsigned short* frag = (unsigned short*)(ws + 16384); // 9.44 MB
  unsigned short* xpad = (unsigned short*)(ws + (16u<<20)); // 72.4 MB padded NHWC bf16

  const int xpad_u4 = B_*XPH*XPW*512/16;                // uint4 count = 4,526,080

  k_style<<<B_, 256, 0, stream>>>(style, mod_w, mod_b, s);
  k_demod<<<B_*C_OUT, 64, 0, stream>>>(weight, s, demod);
  k_pack<<<B_*NKB*16, 64, 0, stream>>>(weight, s, demod, frag);
  k_zero<<<4096, 256, 0, stream>>>((uint4v*)xpad, xpad_u4);
  k_xpose<<<B_*H_*2, 256, 0, stream>>>(x, xpad);
  k_conv<<<B_*2*16*4, NTHR, 0, stream>>>(xpad, frag, out);
}

// Round 6
// 342.567 us; speedup vs baseline: 1.3530x; 1.1980x over previous
//
#include <hip/hip_runtime.h>
#include <hip/hip_bf16.h>

typedef __attribute__((ext_vector_type(8))) short short8;
typedef __attribute__((ext_vector_type(4))) float floatx4;
typedef __attribute__((ext_vector_type(4))) unsigned uint4v;

#define B_ 8
#define C_IN 256
#define C_OUT 256
#define H_ 128
#define W_ 128
#define S_ 512
#define HW_ (H_*W_)
#define LIN_SCALE 0.04419417382415922f   /* 1/sqrt(512) */
#define CONV_SCALE 0.02083333333333333f  /* 1/sqrt(256*9) */
#define EPS_ 1e-8f

#define XPH 130          /* padded H: rows -1..128 -> 0..129 */
#define XPW 136          /* padded W: cols -1..134 -> 0..135 */
#define TTH 8            /* output tile 8h x 32w = 256 px (full 128B out lines) */
#define TTW 32
#define PH2 10           /* halo patch 10 x 34 */
#define PW2 34
#define NPIX2 (PH2*PW2)  /* 340 */
#define NITEM2 (NPIX2*4) /* 1360 16B-items per ci-chunk */
#define NKB 72           /* 8 ci-chunks * 9 taps */
#define NTHR 256         /* 4 waves: 2(M) x 2(N) */

__device__ __forceinline__ unsigned short f2bf(float f) {
  unsigned u = __builtin_bit_cast(unsigned, f);
  u = (u + 0x7fffu + ((u >> 16) & 1u)) >> 16;
  return (unsigned short)u;
}
__device__ __forceinline__ unsigned pack2(float a, float b) {
  return (unsigned)f2bf(a) | ((unsigned)f2bf(b) << 16);
}
__device__ __forceinline__ void gload16(const void* g, void* l) {
  __builtin_amdgcn_global_load_lds(
      (const __attribute__((address_space(1))) unsigned*)g,
      (__attribute__((address_space(3))) unsigned*)l, 16, 0, 0);
}

// ---------------- kernel 1: style modulation s[b][ci] ----------------
__global__ void k_style(const float* __restrict__ style, const float* __restrict__ mw,
                        const float* __restrict__ mb, float* __restrict__ s) {
  __shared__ float sty[S_];
  const int b = blockIdx.x;
  for (int i = threadIdx.x; i < S_; i += 256) sty[i] = style[b*S_ + i];
  __syncthreads();
  const int ci = threadIdx.x;  // 256 threads
  const float* wr = mw + (size_t)ci*S_;
  float acc = 0.f;
  for (int i = 0; i < S_; ++i) acc += sty[i] * wr[i];
  s[b*C_IN + ci] = acc * LIN_SCALE + mb[ci];
}

// ---------------- kernel 2: demod[b][co] ----------------
__global__ void k_demod(const float* __restrict__ weight, const float* __restrict__ s,
                        float* __restrict__ demod) {
  const int b = blockIdx.x >> 8, co = blockIdx.x & 255;
  const int l = threadIdx.x;  // 64 threads
  const float* wrow = weight + (size_t)co*C_IN*9;
  const float* sb = s + b*C_IN;
  float acc = 0.f;
  for (int idx = l; idx < C_IN*9; idx += 64) {
    float wv = wrow[idx] * sb[idx/9];
    acc += wv*wv;
  }
#pragma unroll
  for (int off = 32; off; off >>= 1) acc += __shfl_down(acc, off, 64);
  if (l == 0) demod[blockIdx.x] = rsqrtf(acc * (CONV_SCALE*CONV_SCALE) + EPS_);
}

// ---------------- kernel 3: pack modulated weights into MFMA A-fragment order ----------------
// layout: frag[((b*72 + kb)*16 + mt)*64 + lane][8] bf16, kb = ci_chunk*9 + tap
// A-frag lane l: co = mt*16 + (l&15), k_in = (l>>4)*8 + j, ci = chunk*32 + k_in
__global__ void k_pack(const float* __restrict__ weight, const float* __restrict__ s,
                       const float* __restrict__ demod, unsigned short* __restrict__ frag) {
  const int bid = blockIdx.x;            // (b*72 + kb)*16 + mt
  const int mt = bid & 15;
  const int kb = (bid >> 4) % NKB;
  const int b  = bid / (NKB*16);
  const int l = threadIdx.x;             // 64 threads
  const int co = mt*16 + (l & 15);
  const int chunk = kb / 9, r = kb % 9;
  const float dm = demod[b*C_OUT + co] * CONV_SCALE;
  const float* sb = s + b*C_IN;
  unsigned v[4];
#pragma unroll
  for (int jj = 0; jj < 4; ++jj) {
    int ci0 = chunk*32 + (l >> 4)*8 + jj*2;
    unsigned lo = f2bf(weight[((size_t)co*C_IN + ci0    )*9 + r] * sb[ci0    ] * dm);
    unsigned hi = f2bf(weight[((size_t)co*C_IN + ci0 + 1)*9 + r] * sb[ci0 + 1] * dm);
    v[jj] = lo | (hi << 16);
  }
  unsigned* dst = (unsigned*)(frag + (size_t)bid*512 + l*8);
  dst[0] = v[0]; dst[1] = v[1]; dst[2] = v[2]; dst[3] = v[3];
}

// ---------------- kernel 3b: zero-fill xpad ----------------
__global__ void k_zero(uint4v* __restrict__ p, int n) {
  int i = blockIdx.x*256 + threadIdx.x;
  const int stride = gridDim.x*256;
  const uint4v z = {0u,0u,0u,0u};
  for (; i < n; i += stride) p[i] = z;
}

// ---------------- kernel 3c: NCHW f32 -> chunk-major padded bf16 ----------------
// xpad[b][c][hh][ww][32ci] bf16, c = ci-chunk (8), hh = h+1, ww = w+1; borders 0.
// Chunk-major: a conv ci-chunk's halo read is a contiguous 64 B per pixel
// (fully-consumed L2 lines; round-5 interleaved layout used 64 of 512 B).
__global__ void k_xpose(const float* __restrict__ x, unsigned short* __restrict__ xp) {
  __shared__ __align__(16) unsigned lds32[64*128];   // 32 KB
  const int bid = blockIdx.x;          // 8b * 128h * 2
  const int half = bid & 1, h = (bid >> 1) & 127, b = bid >> 8;
  const int w0 = half*64;
  const int t = threadIdx.x;
  const float* xr = x + (size_t)b*C_IN*HW_ + (size_t)h*W_ + w0;
#pragma unroll
  for (int j = 0; j < 8; ++j) {
    int cp = j*16 + (t >> 4);          // ci-pair 0..127
    int ci = cp*2;
    const float* p0 = xr + (size_t)ci*HW_ + (t & 15)*4;
    floatx4 f0 = *(const floatx4*)p0;
    floatx4 f1 = *(const floatx4*)(p0 + HW_);
    int g = cp >> 2, slot = cp & 3;
#pragma unroll
    for (int k = 0; k < 4; ++k) {
      int px = (t & 15)*4 + k;
      lds32[px*128 + ((g ^ ((px >> 2) & 7)) << 2) + slot] = pack2(f0[k], f1[k]);
    }
  }
  __syncthreads();
#pragma unroll
  for (int i = 0; i < 8; ++i) {
    int item = i*256 + t;
    int px = item >> 5, g = item & 31;       // g = 8-ci group = (c<<2)|sub
    int c = (item >> 2) & 7, sub = item & 3;
    int gs = g ^ ((px >> 2) & 7);
    uint4v v = *(const uint4v*)&lds32[px*128 + (gs << 2)];
    unsigned short* dst = xp +
        (((size_t)(b*8 + c)*XPH + (h + 1))*XPW + (w0 + 1 + px))*32 + sub*8;
    *(uint4v*)dst = v;
  }
}

// ---------------- kernel 4: implicit-GEMM conv ----------------
// block: 128 co (ct half) x (8h x 32w = 256 px), 256 threads, 4 waves 2(M)x2(N)
// wave tile: 64 co x 128 px = 4(m) x 8(n) frags of 16x16; acc = 128 AGPR
// B: async gload16 halo staging, double-buffered LDS, source pre-swizzled.
// A: register rotation — prefetch tap r+1's 4 frags (plain loads; compiler
//    counted-vmcnt) while computing tap r from the other buffer. Removes the
//    round-5 per-r-step global A-load latency + vmcnt FIFO entanglement.
__launch_bounds__(NTHR, 2)
__global__ void k_conv(const unsigned short* __restrict__ xpad,
                       const unsigned short* __restrict__ frag,
                       float* __restrict__ out) {
  __shared__ __align__(16) unsigned char lds[2][1536*16];  // 48 KB -> 2 blocks/CU
  // XCD chunk swizzle: XCD x <- batch x (frag set per XCD stays L2-hot)
  const int work = (blockIdx.x & 7)*128 + (blockIdx.x >> 3);
  const int ct = work & 1;
  const int w2 = work >> 1;
  const int sx = w2 & 3, sy = (w2 >> 2) & 15, b = w2 >> 6;
  const int h0 = sy*TTH, w0 = sx*TTW;
  const int tid = threadIdx.x;
  const int lane = tid & 63, wv = tid >> 6;
  const int wm = wv >> 1, wn = wv & 1;

  const unsigned short* fb = frag + (size_t)b*NKB*16*512 + (size_t)lane*8;

  floatx4 acc[4][8];
#pragma unroll
  for (int m = 0; m < 4; ++m)
#pragma unroll
    for (int n = 0; n < 8; ++n) acc[m][n] = floatx4{0.f, 0.f, 0.f, 0.f};

  auto stageB = [&](int c) {
    unsigned char* buf = lds[c & 1];
    const unsigned short* xc = xpad +
        ((size_t)((b*8 + c)*XPH + h0)*XPW + w0)*32;   // patch origin (pads cancel)
#pragma unroll
    for (int i = 0; i < 6; ++i) {
      int item = tid + i*NTHR;
      if (i < 5 || tid < (NITEM2 - 5*NTHR)) {
        int px = item >> 2, q8s = item & 3;
        int ph = px / PW2, pw = px - ph*PW2;
        int q8 = q8s ^ ((px >> 1) & 3);          // pre-swizzled SOURCE (rule #21)
        const unsigned short* src = xc + ((size_t)ph*XPW + pw)*32 + q8*8;
        gload16(src, buf + item*16);
      }
    }
  };

  short8 pa[4], pb[4];
  auto loadA = [&](short8* dst, int kb) {
#pragma unroll
    for (int m = 0; m < 4; ++m) {
      int mt = ct*8 + wm*4 + m;
      dst[m] = *(const short8*)(fb + (size_t)(kb*16 + mt)*512);
    }
  };

  const int sl = lane >> 4, c15 = lane & 15;
  auto step = [&](const short8* A, int r, const unsigned char* cl) {
    const int dh = r / 3, dw = r % 3;
#pragma unroll
    for (int n = 0; n < 8; ++n) {
      int nt = wn*8 + n;                   // h = nt>>1, w-half = nt&1
      int ph = (nt >> 1) + dh;
      int pw = (nt & 1)*16 + c15 + dw;
      int pix = ph*PW2 + pw;
      int addr = pix*64 + ((sl ^ ((pix >> 1) & 3)) << 4);
      short8 bb = *(const short8*)(cl + addr);
#pragma unroll
      for (int m = 0; m < 4; ++m)
        acc[m][n] = __builtin_amdgcn_mfma_f32_16x16x32_bf16(A[m], bb, acc[m][n], 0, 0, 0);
    }
  };

  stageB(0);
  loadA(pa, 0);          // (c0,r0): buffer parity (c+r)&1 = 0 -> pa
  __syncthreads();       // drains B(0) + pa

  for (int cc = 0; cc < 8; cc += 2) {
    {  // even chunk: r even -> pa, r odd -> pb
      const int c = cc;
      const unsigned char* cl = lds[c & 1];
      stageB(c + 1);
      loadA(pb, c*9 + 1); step(pa, 0, cl);
      loadA(pa, c*9 + 2); step(pb, 1, cl);
      loadA(pb, c*9 + 3); step(pa, 2, cl);
      loadA(pa, c*9 + 4); step(pb, 3, cl);
      loadA(pb, c*9 + 5); step(pa, 4, cl);
      loadA(pa, c*9 + 6); step(pb, 5, cl);
      loadA(pb, c*9 + 7); step(pa, 6, cl);
      loadA(pa, c*9 + 8); step(pb, 7, cl);
      loadA(pb, (c+1)*9); step(pa, 8, cl);   // next chunk r0 -> pb ((c+1+0)&1=1)
      __syncthreads();
    }
    {  // odd chunk: r even -> pb, r odd -> pa
      const int c = cc + 1;
      const unsigned char* cl = lds[c & 1];
      if (c + 1 < 8) stageB(c + 1);
      loadA(pa, c*9 + 1); step(pb, 0, cl);
      loadA(pb, c*9 + 2); step(pa, 1, cl);
      loadA(pa, c*9 + 3); step(pb, 2, cl);
      loadA(pb, c*9 + 4); step(pa, 3, cl);
      loadA(pa, c*9 + 5); step(pb, 4, cl);
      loadA(pb, c*9 + 6); step(pa, 5, cl);
      loadA(pa, c*9 + 7); step(pb, 6, cl);
      loadA(pb, c*9 + 8); step(pa, 7, cl);
      if (c + 1 < 8) loadA(pa, (c+1)*9);     // next chunk r0 -> pa ((c+1+0)&1=0)
      step(pb, 8, cl);
      if (c + 1 < 8) __syncthreads();
    }
  }

  // epilogue: C/D col=lane&15 (pixel w), row=(lane>>4)*4+i (co)
  float* ob = out + ((size_t)b*C_OUT + ct*128)*HW_;
  const int tw = lane & 15, rg = lane >> 4;
#pragma unroll
  for (int m = 0; m < 4; ++m) {
#pragma unroll
    for (int n = 0; n < 8; ++n) {
      int co = (wm*4 + m)*16 + rg*4;
      int nt = wn*8 + n;
      int h = h0 + (nt >> 1);
      int w = w0 + (nt & 1)*16 + tw;
      float* p = ob + (size_t)co*HW_ + (size_t)h*W_ + w;
#pragma unroll
      for (int i = 0; i < 4; ++i) p[i*HW_] = acc[m][n][i];
    }
  }
}

extern "C" void kernel_launch(void* const* d_in, const int* in_sizes, int n_in,
                              void* d_out, int out_size, void* d_ws, size_t ws_size,
                              hipStream_t stream) {
  const float* x      = (const float*)d_in[0];
  const float* style  = (const float*)d_in[1];
  const float* weight = (const float*)d_in[2];
  const float* mod_w  = (const float*)d_in[3];
  const float* mod_b  = (const float*)d_in[4];
  float* out = (float*)d_out;
  char* ws = (char*)d_ws;

  float* s     = (float*)ws;                            // 8 KB
  float* demod = (float*)(ws + 8192);                   // 8 KB
  unsigned short* frag = (unsigned short*)(ws + 16384); // 9.44 MB
  unsigned short* xpad = (unsigned short*)(ws + (16u<<20)); // 72.4 MB chunk-major bf16

  const int xpad_u4 = B_*8*XPH*XPW*32/8;                // uint4 count

  k_style<<<B_, 256, 0, stream>>>(style, mod_w, mod_b, s);
  k_demod<<<B_*C_OUT, 64, 0, stream>>>(weight, s, demod);
  k_pack<<<B_*NKB*16, 64, 0, stream>>>(weight, s, demod, frag);
  k_zero<<<4096, 256, 0, stream>>>((uint4v*)xpad, xpad_u4);
  k_xpose<<<B_*H_*2, 256, 0, stream>>>(x, xpad);
  k_conv<<<B_*2*16*4, NTHR, 0, stream>>>(xpad, frag, out);
}